// Round 2
// baseline (1135.989 us; speedup 1.0000x reference)
//
#include <hip/hip_runtime.h>
#include <stdint.h>

typedef unsigned short u16;
typedef __bf16 bf16_t;
typedef __attribute__((__ext_vector_type__(8))) __bf16 bf16x8;
typedef __attribute__((__ext_vector_type__(4))) float f32x4;

#define BB 8
#define SS 1024
#define EE 512
#define HH 8
#define M1 (BB*SS)      /* 8192 */
#define NQKV (3*HH*EE)  /* 12288 */
#define CDIM (HH*EE)    /* 4096 */

__device__ __forceinline__ u16 f2bf(float x) {
  union { float f; unsigned u; } v; v.f = x;
  unsigned r = (v.u + 0x7fffu + ((v.u >> 16) & 1u)) >> 16;
  return (u16)r;
}
__device__ __forceinline__ float bf2f(u16 h) {
  union { unsigned u; float f; } v; v.u = ((unsigned)h) << 16;
  return v.f;
}
__device__ __forceinline__ void gl_lds16(const void* g, void* l) {
  __builtin_amdgcn_global_load_lds(
      (__attribute__((address_space(1))) void*)(g),
      (__attribute__((address_space(3))) void*)(l), 16, 0, 0);
}

// ---------------- K0a: x fp32 -> bf16 ----------------
__global__ void k_cvt_x(const float* __restrict__ x, u16* __restrict__ xb) {
  int i = (blockIdx.x * 256 + threadIdx.x) * 4;
  float4 v = *(const float4*)(x + i);
  uint2 p;
  p.x = (unsigned)f2bf(v.x) | ((unsigned)f2bf(v.y) << 16);
  p.y = (unsigned)f2bf(v.z) | ((unsigned)f2bf(v.w) << 16);
  *(uint2*)(xb + i) = p;
}

// ------------- K0b: transpose fp32 [R][C] -> bf16 [C][R] (batched z) -------------
__global__ void k_transpose(const float* __restrict__ src, u16* __restrict__ dst,
                            int R, int C) {
  __shared__ float t[32][33];
  int z = blockIdx.z;
  src += (size_t)z * R * C;
  dst += (size_t)z * R * C;
  int r0 = blockIdx.y * 32, c0 = blockIdx.x * 32;
  int lx = threadIdx.x & 31, ly = threadIdx.x >> 5;  // 256 threads
#pragma unroll
  for (int j = 0; j < 32; j += 8)
    t[ly + j][lx] = src[(size_t)(r0 + ly + j) * C + c0 + lx];
  __syncthreads();
#pragma unroll
  for (int j = 0; j < 32; j += 8)
    dst[(size_t)(c0 + ly + j) * R + r0 + lx] = f2bf(t[lx][ly + j]);
}

// ---------------- K1: QKV projection GEMM ----------------
// A = xb [8192][512], B = wt [p][h][f][e] viewed as [12288][512]
// p<2 -> natural store to q/k; p==2 -> transposed store to vT[b][h][f][t]
__global__ __launch_bounds__(256, 2) void k_gemm_qkv(
    const u16* __restrict__ xb, const u16* __restrict__ wt,
    const float* __restrict__ bq, const float* __restrict__ bk,
    const float* __restrict__ bv,
    u16* __restrict__ qws, u16* __restrict__ kws, u16* __restrict__ vt) {
  __shared__ u16 la[128 * 64];
  __shared__ u16 lb[128 * 64];
  __shared__ u16 tb[128 * 136];
  int bid = blockIdx.x;
  int nt = bid % (NQKV / 128);
  int mt = bid / (NQKV / 128);
  int tid = threadIdx.x, lane = tid & 63, w = tid >> 6;
  int wr = w >> 1, wc = w & 1;
  int m0 = mt * 128, n0 = nt * 128;
  f32x4 acc[4][4];
#pragma unroll
  for (int i = 0; i < 4; ++i)
#pragma unroll
    for (int j = 0; j < 4; ++j) acc[i][j] = (f32x4){0.f, 0.f, 0.f, 0.f};

  for (int kt = 0; kt < 512 / 64; ++kt) {
    int k0 = kt * 64;
#pragma unroll
    for (int i = 0; i < 4; ++i) {
      int chunk = i * 256 + w * 64 + lane;
      int row = chunk >> 3, c8 = (chunk & 7) << 3;
      u16* ldsta = la + (size_t)(i * 256 + w * 64) * 8;
      u16* ldstb = lb + (size_t)(i * 256 + w * 64) * 8;
      gl_lds16(xb + (size_t)(m0 + row) * 512 + k0 + c8, ldsta);
      gl_lds16(wt + (size_t)(n0 + row) * 512 + k0 + c8, ldstb);
    }
    __syncthreads();
#pragma unroll
    for (int kk = 0; kk < 2; ++kk) {
      bf16x8 af[4], bg[4];
#pragma unroll
      for (int mi = 0; mi < 4; ++mi)
        af[mi] = *(const bf16x8*)(la + (wr * 64 + mi * 16 + (lane & 15)) * 64 +
                                  kk * 32 + ((lane >> 4) << 3));
#pragma unroll
      for (int ni = 0; ni < 4; ++ni)
        bg[ni] = *(const bf16x8*)(lb + (wc * 64 + ni * 16 + (lane & 15)) * 64 +
                                  kk * 32 + ((lane >> 4) << 3));
#pragma unroll
      for (int mi = 0; mi < 4; ++mi)
#pragma unroll
        for (int ni = 0; ni < 4; ++ni)
          acc[mi][ni] = __builtin_amdgcn_mfma_f32_16x16x32_bf16(
              af[mi], bg[ni], acc[mi][ni], 0, 0, 0);
    }
    __syncthreads();
  }

  int p = n0 >> 12;
  int h = (n0 >> 9) & 7;
  int f0 = n0 & 511;
  int b = m0 >> 10, s0l = m0 & 1023;
  const float* bias = (p == 0) ? bq : (p == 1) ? bk : bv;
  if (p < 2) {
    u16* dst = (p == 0) ? qws : kws;
    size_t base = (size_t)b * 4194304 + (size_t)h * 524288;
#pragma unroll
    for (int mi = 0; mi < 4; ++mi)
#pragma unroll
      for (int ni = 0; ni < 4; ++ni)
#pragma unroll
        for (int j = 0; j < 4; ++j) {
          int r = wr * 64 + mi * 16 + ((lane >> 4) << 2) + j;
          int c = wc * 64 + ni * 16 + (lane & 15);
          float val = acc[mi][ni][j] + bias[h * 512 + f0 + c];
          dst[base + (size_t)(s0l + r) * 512 + f0 + c] = f2bf(val);
        }
  } else {
    size_t base = (size_t)b * 4194304 + (size_t)h * 524288;
#pragma unroll
    for (int mi = 0; mi < 4; ++mi)
#pragma unroll
      for (int ni = 0; ni < 4; ++ni)
#pragma unroll
        for (int j = 0; j < 4; ++j) {
          int r = wr * 64 + mi * 16 + ((lane >> 4) << 2) + j;
          int c = wc * 64 + ni * 16 + (lane & 15);
          tb[c * 136 + r] = f2bf(acc[mi][ni][j] + bias[h * 512 + f0 + c]);
        }
    __syncthreads();
#pragma unroll
    for (int i = 0; i < 8; ++i) {
      int chunk = i * 256 + tid;       // 2048 chunks of 8 elems
      int c = chunk >> 4;
      int r8 = (chunk & 15) << 3;
      *(uint4*)(vt + base + (size_t)(f0 + c) * 1024 + s0l + r8) =
          *(const uint4*)(tb + c * 136 + r8);
    }
  }
}

// ---------------- K2: flash attention per (b,h, 64-row q tile) ----------------
// Pipelined: K/V tiles staged global->regs (issued under compute), regs->LDS at
// top of next iteration. lds_v XOR-swizzled. PV waves 2r x 4f (0.625 LDS
// reads/MFMA). Row sums in registers via shfl butterfly.
__global__ __launch_bounds__(512, 2) void k_attn(
    const u16* __restrict__ q, const u16* __restrict__ k,
    const u16* __restrict__ v, u16* __restrict__ o) {
  __shared__ u16 lds_k[64 * 520];   // K tile (also q staging), padded rows
  __shared__ u16 lds_v[512 * 64];   // V^T tile, XOR-swizzled chunks
  __shared__ u16 lds_p[64 * 72];    // P tile bf16
  __shared__ float l_part[2][64];
  __shared__ float linv_lds[64];
  int bh = blockIdx.y;
  int s0 = blockIdx.x * 64;
  const u16* qb = q + (size_t)bh * 524288;
  const u16* kb = k + (size_t)bh * 524288;
  const u16* vb = v + (size_t)bh * 524288;
  u16* ob = o + (size_t)bh * 524288;
  int tid = threadIdx.x, lane = tid & 63, w = tid >> 6;
  int wr = w >> 1, wc = w & 1;          // QK tiling: 4 row-grp x 2 col-grp
  int rgrp = w & 1, fgrp = w >> 1;      // PV tiling: 2 row-grp x 4 f-grp
  const float scale = 0.044194173824159216f;  // 1/sqrt(512)

  uint4 stk[8], stv[8];
  auto issue_loads = [&](int t0) {
#pragma unroll
    for (int i = 0; i < 8; ++i)
      stk[i] = *(const uint4*)(kb + (size_t)(t0 + i * 8 + (tid >> 6)) * 512 +
                               ((tid & 63) << 3));
#pragma unroll
    for (int i = 0; i < 8; ++i) {
      int chunk = i * 512 + tid;
      stv[i] = *(const uint4*)(vb + (size_t)(chunk >> 3) * 1024 + t0 +
                               ((chunk & 7) << 3));
    }
  };

  // prologue: q tile -> regs, then K/V tile 0 -> regs (stay in flight)
  uint4 qst[8];
#pragma unroll
  for (int i = 0; i < 8; ++i)
    qst[i] = *(const uint4*)(qb + (size_t)(s0 + i * 8 + (tid >> 6)) * 512 +
                             ((tid & 63) << 3));
  issue_loads(0);
#pragma unroll
  for (int i = 0; i < 8; ++i)
    *(uint4*)(lds_k + (i * 8 + (tid >> 6)) * 520 + ((tid & 63) << 3)) = qst[i];
  __syncthreads();
  bf16x8 qf[16];
#pragma unroll
  for (int ks = 0; ks < 16; ++ks)
    qf[ks] = *(const bf16x8*)(lds_k + (wr * 16 + (lane & 15)) * 520 + ks * 32 +
                              ((lane >> 4) << 3));
  f32x4 acc[2][8];
#pragma unroll
  for (int i = 0; i < 2; ++i)
#pragma unroll
    for (int j = 0; j < 8; ++j) acc[i][j] = (f32x4){0.f, 0.f, 0.f, 0.f};
  float rs[4] = {0.f, 0.f, 0.f, 0.f};
  __syncthreads();

  for (int kt = 0; kt < 16; ++kt) {
    // write staged K,V regs -> LDS (compiler inserts the vmcnt wait here)
#pragma unroll
    for (int i = 0; i < 8; ++i)
      *(uint4*)(lds_k + (i * 8 + (tid >> 6)) * 520 + ((tid & 63) << 3)) = stk[i];
#pragma unroll
    for (int i = 0; i < 8; ++i) {
      int chunk = i * 512 + tid;
      int f = chunk >> 3, c3 = chunk & 7;
      *(uint4*)(lds_v + f * 64 + ((c3 ^ (f & 7)) << 3)) = stv[i];
    }
    __syncthreads();
    if (kt < 15) issue_loads((kt + 1) * 64);  // overlap with all compute below

    // ---- QK^T: wave (wr,wc) rows [wr*16,+16), cols [wc*32,+32) ----
    f32x4 as0 = (f32x4){0.f, 0.f, 0.f, 0.f};
    f32x4 as1 = (f32x4){0.f, 0.f, 0.f, 0.f};
    __builtin_amdgcn_s_setprio(1);
#pragma unroll
    for (int ks = 0; ks < 16; ++ks) {
      bf16x8 b0 = *(const bf16x8*)(lds_k + (wc * 32 + (lane & 15)) * 520 +
                                   ks * 32 + ((lane >> 4) << 3));
      bf16x8 b1 = *(const bf16x8*)(lds_k + (wc * 32 + 16 + (lane & 15)) * 520 +
                                   ks * 32 + ((lane >> 4) << 3));
      as0 = __builtin_amdgcn_mfma_f32_16x16x32_bf16(qf[ks], b0, as0, 0, 0, 0);
      as1 = __builtin_amdgcn_mfma_f32_16x16x32_bf16(qf[ks], b1, as1, 0, 0, 0);
    }
    __builtin_amdgcn_s_setprio(0);

    // ---- exp, P write, register row-sums (16-lane butterfly) ----
#pragma unroll
    for (int j = 0; j < 4; ++j) {
      int r = wr * 16 + ((lane >> 4) << 2) + j;
      u16 p0 = f2bf(__expf(as0[j] * scale));
      u16 p1 = f2bf(__expf(as1[j] * scale));
      lds_p[r * 72 + wc * 32 + (lane & 15)] = p0;
      lds_p[r * 72 + wc * 32 + 16 + (lane & 15)] = p1;
      float s = bf2f(p0) + bf2f(p1);
      s += __shfl_xor(s, 1, 64);
      s += __shfl_xor(s, 2, 64);
      s += __shfl_xor(s, 4, 64);
      s += __shfl_xor(s, 8, 64);
      rs[j] += s;
    }
    __syncthreads();

    // ---- PV: wave (rgrp,fgrp) rows [rgrp*32,+32), cols [fgrp*128,+128) ----
    __builtin_amdgcn_s_setprio(1);
#pragma unroll
    for (int ks2 = 0; ks2 < 2; ++ks2) {
      bf16x8 pa0 = *(const bf16x8*)(lds_p + (rgrp * 32 + (lane & 15)) * 72 +
                                    ks2 * 32 + ((lane >> 4) << 3));
      bf16x8 pa1 = *(const bf16x8*)(lds_p + (rgrp * 32 + 16 + (lane & 15)) * 72 +
                                    ks2 * 32 + ((lane >> 4) << 3));
#pragma unroll
      for (int ntl = 0; ntl < 8; ++ntl) {
        int f = fgrp * 128 + ntl * 16 + (lane & 15);
        int g = ks2 * 4 + (lane >> 4);
        bf16x8 vf = *(const bf16x8*)(lds_v + f * 64 + ((g ^ (f & 7)) << 3));
        acc[0][ntl] = __builtin_amdgcn_mfma_f32_16x16x32_bf16(pa0, vf, acc[0][ntl], 0, 0, 0);
        acc[1][ntl] = __builtin_amdgcn_mfma_f32_16x16x32_bf16(pa1, vf, acc[1][ntl], 0, 0, 0);
      }
    }
    __builtin_amdgcn_s_setprio(0);
    __syncthreads();
  }

  // combine per-wave row-sum halves, invert once
  if ((lane & 15) == 0) {
#pragma unroll
    for (int j = 0; j < 4; ++j)
      l_part[wc][wr * 16 + ((lane >> 4) << 2) + j] = rs[j];
  }
  __syncthreads();
  if (tid < 64) linv_lds[tid] = 1.f / (l_part[0][tid] + l_part[1][tid]);
  __syncthreads();
  float li[2][4];
#pragma unroll
  for (int rb = 0; rb < 2; ++rb)
#pragma unroll
    for (int j = 0; j < 4; ++j)
      li[rb][j] = linv_lds[rgrp * 32 + rb * 16 + ((lane >> 4) << 2) + j];
#pragma unroll
  for (int rb = 0; rb < 2; ++rb)
#pragma unroll
    for (int ntl = 0; ntl < 8; ++ntl)
#pragma unroll
      for (int j = 0; j < 4; ++j) {
        int r = rgrp * 32 + rb * 16 + ((lane >> 4) << 2) + j;
        int c = fgrp * 128 + ntl * 16 + (lane & 15);
        ob[(size_t)(s0 + r) * 512 + c] = f2bf(acc[rb][ntl][j] * li[rb][j]);
      }
}

// ---------------- K3: output projection GEMM ----------------
// A = o [b][h][s][f] viewed as [8192][4096], B = woT [512][4096], out fp32
__global__ __launch_bounds__(256, 2) void k_gemm_out(
    const u16* __restrict__ o, const u16* __restrict__ woT,
    const float* __restrict__ bo, float* __restrict__ out) {
  __shared__ u16 la[128 * 64];
  __shared__ u16 lb[128 * 64];
  int nt = blockIdx.x & 3, mt = blockIdx.x >> 2;
  int tid = threadIdx.x, lane = tid & 63, w = tid >> 6;
  int wr = w >> 1, wc = w & 1;
  int m0 = mt * 128, n0 = nt * 128;
  int b = m0 >> 10, s0l = m0 & 1023;
  f32x4 acc[4][4];
#pragma unroll
  for (int i = 0; i < 4; ++i)
#pragma unroll
    for (int j = 0; j < 4; ++j) acc[i][j] = (f32x4){0.f, 0.f, 0.f, 0.f};

  for (int kt = 0; kt < CDIM / 64; ++kt) {
    int k0 = kt * 64;
    int h = k0 >> 9, f0 = k0 & 511;
#pragma unroll
    for (int i = 0; i < 4; ++i) {
      int chunk = i * 256 + w * 64 + lane;
      int row = chunk >> 3, c8 = (chunk & 7) << 3;
      u16* ldsta = la + (size_t)(i * 256 + w * 64) * 8;
      u16* ldstb = lb + (size_t)(i * 256 + w * 64) * 8;
      gl_lds16(o + (size_t)b * 4194304 + (size_t)h * 524288 +
                   (size_t)(s0l + row) * 512 + f0 + c8, ldsta);
      gl_lds16(woT + (size_t)(n0 + row) * 4096 + k0 + c8, ldstb);
    }
    __syncthreads();
#pragma unroll
    for (int kk = 0; kk < 2; ++kk) {
      bf16x8 af[4], bg[4];
#pragma unroll
      for (int mi = 0; mi < 4; ++mi)
        af[mi] = *(const bf16x8*)(la + (wr * 64 + mi * 16 + (lane & 15)) * 64 +
                                  kk * 32 + ((lane >> 4) << 3));
#pragma unroll
      for (int ni = 0; ni < 4; ++ni)
        bg[ni] = *(const bf16x8*)(lb + (wc * 64 + ni * 16 + (lane & 15)) * 64 +
                                  kk * 32 + ((lane >> 4) << 3));
#pragma unroll
      for (int mi = 0; mi < 4; ++mi)
#pragma unroll
        for (int ni = 0; ni < 4; ++ni)
          acc[mi][ni] = __builtin_amdgcn_mfma_f32_16x16x32_bf16(
              af[mi], bg[ni], acc[mi][ni], 0, 0, 0);
    }
    __syncthreads();
  }
#pragma unroll
  for (int mi = 0; mi < 4; ++mi)
#pragma unroll
    for (int ni = 0; ni < 4; ++ni)
#pragma unroll
      for (int j = 0; j < 4; ++j) {
        int r = wr * 64 + mi * 16 + ((lane >> 4) << 2) + j;
        int c = wc * 64 + ni * 16 + (lane & 15);
        out[(size_t)(m0 + r) * 512 + n0 + c] = acc[mi][ni][j] + bo[n0 + c];
      }
}

extern "C" void kernel_launch(void* const* d_in, const int* in_sizes, int n_in,
                              void* d_out, int out_size, void* d_ws, size_t ws_size,
                              hipStream_t stream) {
  const float* x  = (const float*)d_in[0];
  const float* Wq = (const float*)d_in[1];
  const float* Wk = (const float*)d_in[2];
  const float* Wv = (const float*)d_in[3];
  const float* bq = (const float*)d_in[4];
  const float* bk = (const float*)d_in[5];
  const float* bv = (const float*)d_in[6];
  const float* Wo = (const float*)d_in[7];
  const float* bo = (const float*)d_in[8];
  float* out = (float*)d_out;
  char* ws = (char*)d_ws;
  // ws layout (bytes):
  u16* xb  = (u16*)(ws);                  //  8 MB  x bf16 [8192][512]
  u16* wt  = (u16*)(ws + 8388608);        // 12 MB  [3][8][512f][512e]
  u16* woT = (u16*)(ws + 20971520);       //  4 MB  [512][4096]
  u16* qo  = (u16*)(ws + 25165824);       // 64 MB  q, later overwritten by o
  u16* kws = (u16*)(ws + 92274688);       // 64 MB  k
  u16* vT  = (u16*)(ws + 159383552);      // 64 MB  v^T [b][h][f][t]
  // total 216 MB

  k_cvt_x<<<4096, 256, 0, stream>>>(x, xb);
  k_transpose<<<dim3(16, 16, 8), 256, 0, stream>>>(Wq, wt + 0,       512, 512);
  k_transpose<<<dim3(16, 16, 8), 256, 0, stream>>>(Wk, wt + 2097152, 512, 512);
  k_transpose<<<dim3(16, 16, 8), 256, 0, stream>>>(Wv, wt + 4194304, 512, 512);
  k_transpose<<<dim3(16, 128, 1), 256, 0, stream>>>(Wo, woT, 4096, 512);
  k_gemm_qkv<<<6144, 256, 0, stream>>>(xb, wt, bq, bk, bv, qo, kws, vT);
  k_attn<<<dim3(16, 64), 512, 0, stream>>>(qo, kws, vT, qo);
  k_gemm_out<<<256, 256, 0, stream>>>(qo, woT, bo, out);
}

// Round 3
// 783.603 us; speedup vs baseline: 1.4497x; 1.4497x over previous
//
#include <hip/hip_runtime.h>
#include <stdint.h>

typedef unsigned short u16;
typedef __bf16 bf16_t;
typedef __attribute__((__ext_vector_type__(8))) __bf16 bf16x8;
typedef __attribute__((__ext_vector_type__(4))) float f32x4;

#define BB 8
#define SS 1024
#define EE 512
#define HH 8
#define M1 (BB*SS)      /* 8192 */
#define NQKV (3*HH*EE)  /* 12288 */
#define CDIM (HH*EE)    /* 4096 */

__device__ __forceinline__ u16 f2bf(float x) {
  union { float f; unsigned u; } v; v.f = x;
  unsigned r = (v.u + 0x7fffu + ((v.u >> 16) & 1u)) >> 16;
  return (u16)r;
}
__device__ __forceinline__ float bf2f(u16 h) {
  union { unsigned u; float f; } v; v.u = ((unsigned)h) << 16;
  return v.f;
}
__device__ __forceinline__ void gl_lds16(const void* g, void* l) {
  __builtin_amdgcn_global_load_lds(
      (__attribute__((address_space(1))) void*)(g),
      (__attribute__((address_space(3))) void*)(l), 16, 0, 0);
}

// ---------------- K0a: x fp32 -> bf16 ----------------
__global__ void k_cvt_x(const float* __restrict__ x, u16* __restrict__ xb) {
  int i = (blockIdx.x * 256 + threadIdx.x) * 4;
  float4 v = *(const float4*)(x + i);
  uint2 p;
  p.x = (unsigned)f2bf(v.x) | ((unsigned)f2bf(v.y) << 16);
  p.y = (unsigned)f2bf(v.z) | ((unsigned)f2bf(v.w) << 16);
  *(uint2*)(xb + i) = p;
}

// ------------- K0b: transpose fp32 [R][C] -> bf16 [C][R] (batched z) -------------
__global__ void k_transpose(const float* __restrict__ src, u16* __restrict__ dst,
                            int R, int C) {
  __shared__ float t[32][33];
  int z = blockIdx.z;
  src += (size_t)z * R * C;
  dst += (size_t)z * R * C;
  int r0 = blockIdx.y * 32, c0 = blockIdx.x * 32;
  int lx = threadIdx.x & 31, ly = threadIdx.x >> 5;  // 256 threads
#pragma unroll
  for (int j = 0; j < 32; j += 8)
    t[ly + j][lx] = src[(size_t)(r0 + ly + j) * C + c0 + lx];
  __syncthreads();
#pragma unroll
  for (int j = 0; j < 32; j += 8)
    dst[(size_t)(c0 + ly + j) * R + r0 + lx] = f2bf(t[lx][ly + j]);
}

// ---------------- K1: QKV projection GEMM ----------------
// A = xb [8192][512], B = wt [p][h][f][e] viewed as [12288][512]
// p<2 -> natural store to q/k; p==2 -> transposed store to vT[b][h][f][t]
__global__ __launch_bounds__(256, 2) void k_gemm_qkv(
    const u16* __restrict__ xb, const u16* __restrict__ wt,
    const float* __restrict__ bq, const float* __restrict__ bk,
    const float* __restrict__ bv,
    u16* __restrict__ qws, u16* __restrict__ kws, u16* __restrict__ vt) {
  __shared__ u16 la[128 * 64];
  __shared__ u16 lb[128 * 64];
  __shared__ u16 tb[128 * 136];
  int bid = blockIdx.x;
  int nt = bid % (NQKV / 128);
  int mt = bid / (NQKV / 128);
  int tid = threadIdx.x, lane = tid & 63, w = tid >> 6;
  int wr = w >> 1, wc = w & 1;
  int m0 = mt * 128, n0 = nt * 128;
  f32x4 acc[4][4];
#pragma unroll
  for (int i = 0; i < 4; ++i)
#pragma unroll
    for (int j = 0; j < 4; ++j) acc[i][j] = (f32x4){0.f, 0.f, 0.f, 0.f};

  for (int kt = 0; kt < 512 / 64; ++kt) {
    int k0 = kt * 64;
#pragma unroll
    for (int i = 0; i < 4; ++i) {
      int chunk = i * 256 + w * 64 + lane;
      int row = chunk >> 3, c8 = (chunk & 7) << 3;
      u16* ldsta = la + (size_t)(i * 256 + w * 64) * 8;
      u16* ldstb = lb + (size_t)(i * 256 + w * 64) * 8;
      gl_lds16(xb + (size_t)(m0 + row) * 512 + k0 + c8, ldsta);
      gl_lds16(wt + (size_t)(n0 + row) * 512 + k0 + c8, ldstb);
    }
    __syncthreads();
#pragma unroll
    for (int kk = 0; kk < 2; ++kk) {
      bf16x8 af[4], bg[4];
#pragma unroll
      for (int mi = 0; mi < 4; ++mi)
        af[mi] = *(const bf16x8*)(la + (wr * 64 + mi * 16 + (lane & 15)) * 64 +
                                  kk * 32 + ((lane >> 4) << 3));
#pragma unroll
      for (int ni = 0; ni < 4; ++ni)
        bg[ni] = *(const bf16x8*)(lb + (wc * 64 + ni * 16 + (lane & 15)) * 64 +
                                  kk * 32 + ((lane >> 4) << 3));
#pragma unroll
      for (int mi = 0; mi < 4; ++mi)
#pragma unroll
        for (int ni = 0; ni < 4; ++ni)
          acc[mi][ni] = __builtin_amdgcn_mfma_f32_16x16x32_bf16(
              af[mi], bg[ni], acc[mi][ni], 0, 0, 0);
    }
    __syncthreads();
  }

  int p = n0 >> 12;
  int h = (n0 >> 9) & 7;
  int f0 = n0 & 511;
  int b = m0 >> 10, s0l = m0 & 1023;
  const float* bias = (p == 0) ? bq : (p == 1) ? bk : bv;
  if (p < 2) {
    u16* dst = (p == 0) ? qws : kws;
    size_t base = (size_t)b * 4194304 + (size_t)h * 524288;
#pragma unroll
    for (int mi = 0; mi < 4; ++mi)
#pragma unroll
      for (int ni = 0; ni < 4; ++ni)
#pragma unroll
        for (int j = 0; j < 4; ++j) {
          int r = wr * 64 + mi * 16 + ((lane >> 4) << 2) + j;
          int c = wc * 64 + ni * 16 + (lane & 15);
          float val = acc[mi][ni][j] + bias[h * 512 + f0 + c];
          dst[base + (size_t)(s0l + r) * 512 + f0 + c] = f2bf(val);
        }
  } else {
    size_t base = (size_t)b * 4194304 + (size_t)h * 524288;
#pragma unroll
    for (int mi = 0; mi < 4; ++mi)
#pragma unroll
      for (int ni = 0; ni < 4; ++ni)
#pragma unroll
        for (int j = 0; j < 4; ++j) {
          int r = wr * 64 + mi * 16 + ((lane >> 4) << 2) + j;
          int c = wc * 64 + ni * 16 + (lane & 15);
          tb[c * 136 + r] = f2bf(acc[mi][ni][j] + bias[h * 512 + f0 + c]);
        }
    __syncthreads();
#pragma unroll
    for (int i = 0; i < 8; ++i) {
      int chunk = i * 256 + tid;       // 2048 chunks of 8 elems
      int c = chunk >> 4;
      int r8 = (chunk & 15) << 3;
      *(uint4*)(vt + base + (size_t)(f0 + c) * 1024 + s0l + r8) =
          *(const uint4*)(tb + c * 136 + r8);
    }
  }
}

// ---------------- K2: flash attention, 16 waves, gl_lds staging ----------------
// One block per (b,h, 64-row q tile), 1024 threads = 16 waves.
// QK tiling 4r x 4c (wave: 16 rows x 16 cols); PV tiling 4r x 4f (16 rows x 128 f).
// K [64][512] and V^T [512][64] staged linear-LDS via global_load_lds with
// XOR-pre-swizzled per-lane SOURCE addresses (swizzle c8 ^= row&7); reads use
// the same XOR -> conflict-free. Counted vmcnt + raw s_barrier: V(kt) flies
// under QK, K(kt+1) under PV.
__global__ __launch_bounds__(1024, 4) void k_attn(
    const u16* __restrict__ q, const u16* __restrict__ k,
    const u16* __restrict__ v, u16* __restrict__ o) {
  __shared__ u16 lds_k[64 * 512];   // 64 KB
  __shared__ u16 lds_v[512 * 64];   // 64 KB
  __shared__ u16 lds_p[64 * 72];    //  9 KB
  __shared__ float l_part[4][64];
  __shared__ float linv_lds[64];
  int bh = blockIdx.y;
  int s0 = blockIdx.x * 64;
  const u16* qb = q + (size_t)bh * 524288;
  const u16* kb = k + (size_t)bh * 524288;
  const u16* vb = v + (size_t)bh * 524288;
  u16* ob = o + (size_t)bh * 524288;
  int tid = threadIdx.x, lane = tid & 63, w = tid >> 6;
  int wr = w >> 2, wc = w & 3;
  int g = lane >> 4, l15 = lane & 15, l7 = lane & 7;
  const float scale = 0.044194173824159216f;  // 1/sqrt(512)

  auto issue_k = [&](int t0) {
#pragma unroll
    for (int i = 0; i < 4; ++i) {
      int row = i * 16 + w;                       // wave-uniform row
      gl_lds16(kb + (size_t)(t0 + row) * 512 + ((lane ^ (row & 7)) << 3),
               lds_k + row * 512);
    }
  };
  auto issue_v = [&](int t0) {
#pragma unroll
    for (int i = 0; i < 4; ++i) {
      int f = i * 128 + w * 8 + (lane >> 3);      // 8 rows per wave-issue
      gl_lds16(vb + (size_t)f * 1024 + t0 + (((lane & 7) ^ (f & 7)) << 3),
               lds_v + (i * 128 + w * 8) * 64);   // wave-uniform base
    }
  };

  // ---- prologue: K(0) in flight; Q fragments global->regs ----
  issue_k(0);
  bf16x8 qf[16];
  {
    const u16* qrow = qb + (size_t)(s0 + wr * 16 + l15) * 512;
#pragma unroll
    for (int ks = 0; ks < 16; ++ks)
      qf[ks] = *(const bf16x8*)(qrow + ks * 32 + (g << 3));
  }
  f32x4 acc[8];
#pragma unroll
  for (int i = 0; i < 8; ++i) acc[i] = (f32x4){0.f, 0.f, 0.f, 0.f};
  float rs[4] = {0.f, 0.f, 0.f, 0.f};

  for (int kt = 0; kt < 16; ++kt) {
    int t0 = kt * 64;
    issue_v(t0);                                   // flies under QK
    asm volatile("s_waitcnt vmcnt(4)" ::: "memory");  // K(kt)+Q done, V may fly
    __builtin_amdgcn_s_barrier();                  // B1: K(kt) visible

    // ---- QK^T: wave (wr,wc): rows wr*16, cols wc*16 ----
    f32x4 as = (f32x4){0.f, 0.f, 0.f, 0.f};
    __builtin_amdgcn_s_setprio(1);
#pragma unroll
    for (int ks = 0; ks < 16; ++ks) {
      bf16x8 b0 = *(const bf16x8*)(lds_k + (wc * 16 + l15) * 512 +
                                   (((ks * 4 + g) ^ l7) << 3));
      as = __builtin_amdgcn_mfma_f32_16x16x32_bf16(qf[ks], b0, as, 0, 0, 0);
    }
    __builtin_amdgcn_s_setprio(0);

    // ---- exp, P write, register row-sums ----
#pragma unroll
    for (int j = 0; j < 4; ++j) {
      u16 p0 = f2bf(__expf(as[j] * scale));
      lds_p[(wr * 16 + g * 4 + j) * 72 + wc * 16 + l15] = p0;
      float sfl = bf2f(p0);
      sfl += __shfl_xor(sfl, 1, 64);
      sfl += __shfl_xor(sfl, 2, 64);
      sfl += __shfl_xor(sfl, 4, 64);
      sfl += __shfl_xor(sfl, 8, 64);
      rs[j] += sfl;
    }
    asm volatile("s_waitcnt vmcnt(0) lgkmcnt(0)" ::: "memory");  // V + P landed
    __builtin_amdgcn_s_barrier();                  // B2: V,P visible; lds_k free
    if (kt < 15) issue_k(t0 + 64);                 // flies under PV

    // ---- PV: wave (wr,wc): rows wr*16, f-cols wc*128 ----
    __builtin_amdgcn_s_setprio(1);
#pragma unroll
    for (int ks2 = 0; ks2 < 2; ++ks2) {
      bf16x8 pa = *(const bf16x8*)(lds_p + (wr * 16 + l15) * 72 + ks2 * 32 +
                                   (g << 3));
#pragma unroll
      for (int ntl = 0; ntl < 8; ++ntl) {
        int f = wc * 128 + ntl * 16 + l15;
        bf16x8 vf = *(const bf16x8*)(lds_v + f * 64 +
                                     (((ks2 * 4 + g) ^ l7) << 3));
        acc[ntl] = __builtin_amdgcn_mfma_f32_16x16x32_bf16(pa, vf, acc[ntl], 0, 0, 0);
      }
    }
    __builtin_amdgcn_s_setprio(0);
    asm volatile("s_waitcnt lgkmcnt(0)" ::: "memory");  // PV reads drained
    __builtin_amdgcn_s_barrier();                  // B3: lds_v, lds_p free
  }

  // ---- epilogue: combine row sums, scale, store ----
  if (l15 == 0) {
#pragma unroll
    for (int j = 0; j < 4; ++j) l_part[wc][wr * 16 + g * 4 + j] = rs[j];
  }
  asm volatile("s_waitcnt lgkmcnt(0)" ::: "memory");
  __builtin_amdgcn_s_barrier();
  if (tid < 64)
    linv_lds[tid] = 1.f / (l_part[0][tid] + l_part[1][tid] +
                           l_part[2][tid] + l_part[3][tid]);
  asm volatile("s_waitcnt lgkmcnt(0)" ::: "memory");
  __builtin_amdgcn_s_barrier();
  float li[4];
#pragma unroll
  for (int j = 0; j < 4; ++j) li[j] = linv_lds[wr * 16 + g * 4 + j];
#pragma unroll
  for (int ntl = 0; ntl < 8; ++ntl)
#pragma unroll
    for (int j = 0; j < 4; ++j) {
      int r = wr * 16 + g * 4 + j;
      int c = wc * 128 + ntl * 16 + l15;
      ob[(size_t)(s0 + r) * 512 + c] = f2bf(acc[ntl][j] * li[j]);
    }
}

// ---------------- K3: output projection GEMM ----------------
// A = o [b][h][s][f] viewed as [8192][4096], B = woT [512][4096], out fp32
__global__ __launch_bounds__(256, 2) void k_gemm_out(
    const u16* __restrict__ o, const u16* __restrict__ woT,
    const float* __restrict__ bo, float* __restrict__ out) {
  __shared__ u16 la[128 * 64];
  __shared__ u16 lb[128 * 64];
  int nt = blockIdx.x & 3, mt = blockIdx.x >> 2;
  int tid = threadIdx.x, lane = tid & 63, w = tid >> 6;
  int wr = w >> 1, wc = w & 1;
  int m0 = mt * 128, n0 = nt * 128;
  int b = m0 >> 10, s0l = m0 & 1023;
  f32x4 acc[4][4];
#pragma unroll
  for (int i = 0; i < 4; ++i)
#pragma unroll
    for (int j = 0; j < 4; ++j) acc[i][j] = (f32x4){0.f, 0.f, 0.f, 0.f};

  for (int kt = 0; kt < CDIM / 64; ++kt) {
    int k0 = kt * 64;
    int h = k0 >> 9, f0 = k0 & 511;
#pragma unroll
    for (int i = 0; i < 4; ++i) {
      int chunk = i * 256 + w * 64 + lane;
      int row = chunk >> 3, c8 = (chunk & 7) << 3;
      u16* ldsta = la + (size_t)(i * 256 + w * 64) * 8;
      u16* ldstb = lb + (size_t)(i * 256 + w * 64) * 8;
      gl_lds16(o + (size_t)b * 4194304 + (size_t)h * 524288 +
                   (size_t)(s0l + row) * 512 + f0 + c8, ldsta);
      gl_lds16(woT + (size_t)(n0 + row) * 4096 + k0 + c8, ldstb);
    }
    __syncthreads();
#pragma unroll
    for (int kk = 0; kk < 2; ++kk) {
      bf16x8 af[4], bg[4];
#pragma unroll
      for (int mi = 0; mi < 4; ++mi)
        af[mi] = *(const bf16x8*)(la + (wr * 64 + mi * 16 + (lane & 15)) * 64 +
                                  kk * 32 + ((lane >> 4) << 3));
#pragma unroll
      for (int ni = 0; ni < 4; ++ni)
        bg[ni] = *(const bf16x8*)(lb + (wc * 64 + ni * 16 + (lane & 15)) * 64 +
                                  kk * 32 + ((lane >> 4) << 3));
#pragma unroll
      for (int mi = 0; mi < 4; ++mi)
#pragma unroll
        for (int ni = 0; ni < 4; ++ni)
          acc[mi][ni] = __builtin_amdgcn_mfma_f32_16x16x32_bf16(
              af[mi], bg[ni], acc[mi][ni], 0, 0, 0);
    }
    __syncthreads();
  }
#pragma unroll
  for (int mi = 0; mi < 4; ++mi)
#pragma unroll
    for (int ni = 0; ni < 4; ++ni)
#pragma unroll
      for (int j = 0; j < 4; ++j) {
        int r = wr * 64 + mi * 16 + ((lane >> 4) << 2) + j;
        int c = wc * 64 + ni * 16 + (lane & 15);
        out[(size_t)(m0 + r) * 512 + n0 + c] = acc[mi][ni][j] + bo[n0 + c];
      }
}

extern "C" void kernel_launch(void* const* d_in, const int* in_sizes, int n_in,
                              void* d_out, int out_size, void* d_ws, size_t ws_size,
                              hipStream_t stream) {
  const float* x  = (const float*)d_in[0];
  const float* Wq = (const float*)d_in[1];
  const float* Wk = (const float*)d_in[2];
  const float* Wv = (const float*)d_in[3];
  const float* bq = (const float*)d_in[4];
  const float* bk = (const float*)d_in[5];
  const float* bv = (const float*)d_in[6];
  const float* Wo = (const float*)d_in[7];
  const float* bo = (const float*)d_in[8];
  float* out = (float*)d_out;
  char* ws = (char*)d_ws;
  // ws layout (bytes):
  u16* xb  = (u16*)(ws);                  //  8 MB  x bf16 [8192][512]
  u16* wt  = (u16*)(ws + 8388608);        // 12 MB  [3][8][512f][512e]
  u16* woT = (u16*)(ws + 20971520);       //  4 MB  [512][4096]
  u16* qo  = (u16*)(ws + 25165824);       // 64 MB  q, later overwritten by o
  u16* kws = (u16*)(ws + 92274688);       // 64 MB  k
  u16* vT  = (u16*)(ws + 159383552);      // 64 MB  v^T [b][h][f][t]
  // total 216 MB

  k_cvt_x<<<4096, 256, 0, stream>>>(x, xb);
  k_transpose<<<dim3(16, 16, 8), 256, 0, stream>>>(Wq, wt + 0,       512, 512);
  k_transpose<<<dim3(16, 16, 8), 256, 0, stream>>>(Wk, wt + 2097152, 512, 512);
  k_transpose<<<dim3(16, 16, 8), 256, 0, stream>>>(Wv, wt + 4194304, 512, 512);
  k_transpose<<<dim3(16, 128, 1), 256, 0, stream>>>(Wo, woT, 4096, 512);
  k_gemm_qkv<<<6144, 256, 0, stream>>>(xb, wt, bq, bk, bv, qo, kws, vT);
  k_attn<<<dim3(16, 64), 1024, 0, stream>>>(qo, kws, vT, qo);
  k_gemm_out<<<256, 256, 0, stream>>>(qo, woT, bo, out);
}

// Round 4
// 514.056 us; speedup vs baseline: 2.2099x; 1.5244x over previous
//
#include <hip/hip_runtime.h>
#include <stdint.h>

typedef unsigned short u16;
typedef __bf16 bf16_t;
typedef __attribute__((__ext_vector_type__(8))) __bf16 bf16x8;
typedef __attribute__((__ext_vector_type__(4))) float f32x4;

#define BB 8
#define SS 1024
#define EE 512
#define HH 8
#define M1 (BB*SS)      /* 8192 */
#define NQKV (3*HH*EE)  /* 12288 */
#define CDIM (HH*EE)    /* 4096 */

__device__ __forceinline__ u16 f2bf(float x) {
  union { float f; unsigned u; } v; v.f = x;
  unsigned r = (v.u + 0x7fffu + ((v.u >> 16) & 1u)) >> 16;
  return (u16)r;
}
__device__ __forceinline__ float bf2f(u16 h) {
  union { unsigned u; float f; } v; v.u = ((unsigned)h) << 16;
  return v.f;
}
__device__ __forceinline__ void gl_lds16(const void* g, void* l) {
  __builtin_amdgcn_global_load_lds(
      (__attribute__((address_space(1))) void*)(g),
      (__attribute__((address_space(3))) void*)(l), 16, 0, 0);
}

// ---------------- K0a: x fp32 -> bf16 ----------------
__global__ void k_cvt_x(const float* __restrict__ x, u16* __restrict__ xb) {
  int i = (blockIdx.x * 256 + threadIdx.x) * 4;
  float4 v = *(const float4*)(x + i);
  uint2 p;
  p.x = (unsigned)f2bf(v.x) | ((unsigned)f2bf(v.y) << 16);
  p.y = (unsigned)f2bf(v.z) | ((unsigned)f2bf(v.w) << 16);
  *(uint2*)(xb + i) = p;
}

// ------------- K0b: transpose fp32 [R][C] -> bf16 [C][R] (batched z) -------------
__global__ void k_transpose(const float* __restrict__ src, u16* __restrict__ dst,
                            int R, int C) {
  __shared__ float t[32][33];
  int z = blockIdx.z;
  src += (size_t)z * R * C;
  dst += (size_t)z * R * C;
  int r0 = blockIdx.y * 32, c0 = blockIdx.x * 32;
  int lx = threadIdx.x & 31, ly = threadIdx.x >> 5;  // 256 threads
#pragma unroll
  for (int j = 0; j < 32; j += 8)
    t[ly + j][lx] = src[(size_t)(r0 + ly + j) * C + c0 + lx];
  __syncthreads();
#pragma unroll
  for (int j = 0; j < 32; j += 8)
    dst[(size_t)(c0 + ly + j) * R + r0 + lx] = f2bf(t[lx][ly + j]);
}

// ---------------- K1: QKV projection GEMM ----------------
__global__ __launch_bounds__(256, 2) void k_gemm_qkv(
    const u16* __restrict__ xb, const u16* __restrict__ wt,
    const float* __restrict__ bq, const float* __restrict__ bk,
    const float* __restrict__ bv,
    u16* __restrict__ qws, u16* __restrict__ kws, u16* __restrict__ vt) {
  __shared__ u16 la[128 * 64];
  __shared__ u16 lb[128 * 64];
  __shared__ u16 tb[128 * 136];
  int bid = blockIdx.x;
  int nt = bid % (NQKV / 128);
  int mt = bid / (NQKV / 128);
  int tid = threadIdx.x, lane = tid & 63, w = tid >> 6;
  int wr = w >> 1, wc = w & 1;
  int m0 = mt * 128, n0 = nt * 128;
  f32x4 acc[4][4];
#pragma unroll
  for (int i = 0; i < 4; ++i)
#pragma unroll
    for (int j = 0; j < 4; ++j) acc[i][j] = (f32x4){0.f, 0.f, 0.f, 0.f};

  for (int kt = 0; kt < 512 / 64; ++kt) {
    int k0 = kt * 64;
#pragma unroll
    for (int i = 0; i < 4; ++i) {
      int chunk = i * 256 + w * 64 + lane;
      int row = chunk >> 3, c8 = (chunk & 7) << 3;
      u16* ldsta = la + (size_t)(i * 256 + w * 64) * 8;
      u16* ldstb = lb + (size_t)(i * 256 + w * 64) * 8;
      gl_lds16(xb + (size_t)(m0 + row) * 512 + k0 + c8, ldsta);
      gl_lds16(wt + (size_t)(n0 + row) * 512 + k0 + c8, ldstb);
    }
    __syncthreads();
#pragma unroll
    for (int kk = 0; kk < 2; ++kk) {
      bf16x8 af[4], bg[4];
#pragma unroll
      for (int mi = 0; mi < 4; ++mi)
        af[mi] = *(const bf16x8*)(la + (wr * 64 + mi * 16 + (lane & 15)) * 64 +
                                  kk * 32 + ((lane >> 4) << 3));
#pragma unroll
      for (int ni = 0; ni < 4; ++ni)
        bg[ni] = *(const bf16x8*)(lb + (wc * 64 + ni * 16 + (lane & 15)) * 64 +
                                  kk * 32 + ((lane >> 4) << 3));
#pragma unroll
      for (int mi = 0; mi < 4; ++mi)
#pragma unroll
        for (int ni = 0; ni < 4; ++ni)
          acc[mi][ni] = __builtin_amdgcn_mfma_f32_16x16x32_bf16(
              af[mi], bg[ni], acc[mi][ni], 0, 0, 0);
    }
    __syncthreads();
  }

  int p = n0 >> 12;
  int h = (n0 >> 9) & 7;
  int f0 = n0 & 511;
  int b = m0 >> 10, s0l = m0 & 1023;
  const float* bias = (p == 0) ? bq : (p == 1) ? bk : bv;
  if (p < 2) {
    u16* dst = (p == 0) ? qws : kws;
    size_t base = (size_t)b * 4194304 + (size_t)h * 524288;
#pragma unroll
    for (int mi = 0; mi < 4; ++mi)
#pragma unroll
      for (int ni = 0; ni < 4; ++ni)
#pragma unroll
        for (int j = 0; j < 4; ++j) {
          int r = wr * 64 + mi * 16 + ((lane >> 4) << 2) + j;
          int c = wc * 64 + ni * 16 + (lane & 15);
          float val = acc[mi][ni][j] + bias[h * 512 + f0 + c];
          dst[base + (size_t)(s0l + r) * 512 + f0 + c] = f2bf(val);
        }
  } else {
    size_t base = (size_t)b * 4194304 + (size_t)h * 524288;
#pragma unroll
    for (int mi = 0; mi < 4; ++mi)
#pragma unroll
      for (int ni = 0; ni < 4; ++ni)
#pragma unroll
        for (int j = 0; j < 4; ++j) {
          int r = wr * 64 + mi * 16 + ((lane >> 4) << 2) + j;
          int c = wc * 64 + ni * 16 + (lane & 15);
          tb[c * 136 + r] = f2bf(acc[mi][ni][j] + bias[h * 512 + f0 + c]);
        }
    __syncthreads();
#pragma unroll
    for (int i = 0; i < 8; ++i) {
      int chunk = i * 256 + tid;       // 2048 chunks of 8 elems
      int c = chunk >> 4;
      int r8 = (chunk & 15) << 3;
      *(uint4*)(vt + base + (size_t)(f0 + c) * 1024 + s0l + r8) =
          *(const uint4*)(tb + c * 136 + r8);
    }
  }
}

// ---------------- K2: flash attention v4 ----------------
// 8 waves (512 thr), block = 64 q-rows, KVBLK = 64, 16 kt.
// QK: waves (r2,c2,kh2): wave = 32 rows x 32 cols x 256 k (K-frag dup = 2).
//     Partials combined via f32 LDS buffer; kh=1 waves do exp + P + row sums.
// PV: wave w = ALL 64 rows x 64 f-cols (V-frag dup = 1), acc 64 VGPR.
// K/V staged by global_load_lds with XOR-pre-swizzled global sources; reads use
// the same XOR. Counted vmcnt: V(kt) flies under QK, K(kt+1) under exp+PV.
// XCD mapping: the 16 q-tiles of one bh land on one XCD (bh = (n&7)|((n>>7)<<3)).
__global__ __launch_bounds__(512, 2) void k_attn(
    const u16* __restrict__ q, const u16* __restrict__ k,
    const u16* __restrict__ v, u16* o) {
  __shared__ u16 lds_k[64 * 512];     // 64 KB, XOR-swizzled chunks
  __shared__ u16 lds_v[512 * 64];     // 64 KB, XOR-swizzled chunks
  __shared__ float lds_s[64 * 65];    // 16.6 KB score partials
  __shared__ u16 lds_p[64 * 64];      //  8 KB P tile, XOR-swizzled
  __shared__ float l_part[2][64];
  __shared__ float linv_lds[64];
  int n = blockIdx.x;
  int bh = (n & 7) | ((n >> 7) << 3);
  int s0 = ((n >> 3) & 15) * 64;
  const u16* qb = q + (size_t)bh * 524288;
  const u16* kb = k + (size_t)bh * 524288;
  const u16* vb = v + (size_t)bh * 524288;
  u16* ob = o + (size_t)bh * 524288;
  int tid = threadIdx.x, lane = tid & 63, w = tid >> 6;
  int qr = w & 1, qc = (w >> 1) & 1, kh = w >> 2;   // QK wave coords
  int g = lane >> 4, l15 = lane & 15;
  const float scale = 0.044194173824159216f;  // 1/sqrt(512)

  auto issue_k = [&](int t0) {
#pragma unroll
    for (int i = 0; i < 8; ++i) {
      int row = w * 8 + i;                        // wave-uniform
      gl_lds16(kb + (size_t)(t0 + row) * 512 + ((lane ^ (row & 7)) << 3),
               lds_k + row * 512);
    }
  };
  auto issue_v = [&](int t0) {
#pragma unroll
    for (int i = 0; i < 8; ++i) {
      int fb = w * 64 + i * 8;                    // wave-uniform
      int f = fb + (lane >> 3);
      gl_lds16(vb + (size_t)f * 1024 + t0 + (((lane & 7) ^ (f & 7)) << 3),
               lds_v + fb * 64);
    }
  };

  // ---- prologue: Q half-k fragments -> regs, then K(0) in flight ----
  bf16x8 qf[2][8];
#pragma unroll
  for (int rb = 0; rb < 2; ++rb) {
    const u16* qrow = qb + (size_t)(s0 + qr * 32 + rb * 16 + l15) * 512 + kh * 256;
#pragma unroll
    for (int ks = 0; ks < 8; ++ks)
      qf[rb][ks] = *(const bf16x8*)(qrow + ks * 32 + (g << 3));
  }
  issue_k(0);
  f32x4 accp[4][4];
#pragma unroll
  for (int i = 0; i < 4; ++i)
#pragma unroll
    for (int j = 0; j < 4; ++j) accp[i][j] = (f32x4){0.f, 0.f, 0.f, 0.f};
  float rs[2][4] = {{0.f, 0.f, 0.f, 0.f}, {0.f, 0.f, 0.f, 0.f}};

  for (int kt = 0; kt < 16; ++kt) {
    int t0 = kt * 64;
    issue_v(t0);                                   // flies under QK
    asm volatile("s_waitcnt vmcnt(8)" ::: "memory");  // K(kt) (+qf) done
    __builtin_amdgcn_s_barrier();                  // B1: lds_k ready

    // ---- QK^T partial: rows qr*32..+32, cols qc*32..+32, k kh*256..+256 ----
    f32x4 aq[2][2];
#pragma unroll
    for (int rb = 0; rb < 2; ++rb)
#pragma unroll
      for (int cb = 0; cb < 2; ++cb) aq[rb][cb] = (f32x4){0.f, 0.f, 0.f, 0.f};
    __builtin_amdgcn_s_setprio(1);
#pragma unroll
    for (int ks = 0; ks < 8; ++ks) {
      bf16x8 bg[2];
#pragma unroll
      for (int cb = 0; cb < 2; ++cb) {
        int col = qc * 32 + cb * 16 + l15;
        int ch = (kh * 32 + ks * 4 + g) ^ (col & 7);
        bg[cb] = *(const bf16x8*)(lds_k + col * 512 + (ch << 3));
      }
#pragma unroll
      for (int rb = 0; rb < 2; ++rb)
#pragma unroll
        for (int cb = 0; cb < 2; ++cb)
          aq[rb][cb] = __builtin_amdgcn_mfma_f32_16x16x32_bf16(
              qf[rb][ks], bg[cb], aq[rb][cb], 0, 0, 0);
    }
    __builtin_amdgcn_s_setprio(0);

    // ---- combine k-halves ----
    if (kh == 0) {
#pragma unroll
      for (int rb = 0; rb < 2; ++rb)
#pragma unroll
        for (int cb = 0; cb < 2; ++cb)
#pragma unroll
          for (int j = 0; j < 4; ++j) {
            int row = qr * 32 + rb * 16 + g * 4 + j;
            int col = qc * 32 + cb * 16 + l15;
            lds_s[row * 65 + col] = aq[rb][cb][j];
          }
    }
    asm volatile("s_waitcnt lgkmcnt(0)" ::: "memory");
    __builtin_amdgcn_s_barrier();                  // B2: partials visible
    if (kt < 15) issue_k(t0 + 64);                 // flies under exp+PV
    if (kh == 1) {
#pragma unroll
      for (int rb = 0; rb < 2; ++rb)
#pragma unroll
        for (int j = 0; j < 4; ++j) {
          int row = qr * 32 + rb * 16 + g * 4 + j;
          float sf = 0.f;
#pragma unroll
          for (int cb = 0; cb < 2; ++cb) {
            int col = qc * 32 + cb * 16 + l15;
            float sc = lds_s[row * 65 + col] + aq[rb][cb][j];
            u16 pb = f2bf(__expf(sc * scale));
            int ch = (col >> 3) ^ (row & 7);
            lds_p[row * 64 + (ch << 3) + (col & 7)] = pb;
            sf += bf2f(pb);
          }
          sf += __shfl_xor(sf, 1, 64);
          sf += __shfl_xor(sf, 2, 64);
          sf += __shfl_xor(sf, 4, 64);
          sf += __shfl_xor(sf, 8, 64);
          rs[rb][j] += sf;
        }
    }
    if (kt < 15) {
      asm volatile("s_waitcnt vmcnt(8)" ::: "memory");  // V(kt) done, K(kt+1) flies
    } else {
      asm volatile("s_waitcnt vmcnt(0)" ::: "memory");
    }
    asm volatile("s_waitcnt lgkmcnt(0)" ::: "memory");
    __builtin_amdgcn_s_barrier();                  // B3: lds_p, lds_v ready

    // ---- PV: wave w: all 64 rows x f-cols w*64..+64 ----
    __builtin_amdgcn_s_setprio(1);
#pragma unroll
    for (int tf = 0; tf < 2; ++tf) {
      bf16x8 pa[4], vf[4];
#pragma unroll
      for (int ra = 0; ra < 4; ++ra) {
        int row = ra * 16 + l15;
        int ch = (tf * 4 + g) ^ (row & 7);
        pa[ra] = *(const bf16x8*)(lds_p + row * 64 + (ch << 3));
      }
#pragma unroll
      for (int fb = 0; fb < 4; ++fb) {
        int f = w * 64 + fb * 16 + l15;
        int ch = (tf * 4 + g) ^ (f & 7);
        vf[fb] = *(const bf16x8*)(lds_v + f * 64 + (ch << 3));
      }
#pragma unroll
      for (int ra = 0; ra < 4; ++ra)
#pragma unroll
        for (int fb = 0; fb < 4; ++fb)
          accp[ra][fb] = __builtin_amdgcn_mfma_f32_16x16x32_bf16(
              pa[ra], vf[fb], accp[ra][fb], 0, 0, 0);
    }
    __builtin_amdgcn_s_setprio(0);
    asm volatile("s_waitcnt lgkmcnt(0)" ::: "memory");
    __builtin_amdgcn_s_barrier();                  // B4: lds_v/lds_p free
  }

  // ---- epilogue: combine row sums (kh=1 waves hold col-halves per qc) ----
  if (kh == 1 && l15 == 0) {
#pragma unroll
    for (int rb = 0; rb < 2; ++rb)
#pragma unroll
      for (int j = 0; j < 4; ++j)
        l_part[qc][qr * 32 + rb * 16 + g * 4 + j] = rs[rb][j];
  }
  asm volatile("s_waitcnt lgkmcnt(0)" ::: "memory");
  __builtin_amdgcn_s_barrier();
  if (tid < 64) linv_lds[tid] = 1.f / (l_part[0][tid] + l_part[1][tid]);
  asm volatile("s_waitcnt lgkmcnt(0)" ::: "memory");
  __builtin_amdgcn_s_barrier();
  float li[4][4];
#pragma unroll
  for (int ra = 0; ra < 4; ++ra)
#pragma unroll
    for (int j = 0; j < 4; ++j) li[ra][j] = linv_lds[ra * 16 + g * 4 + j];
#pragma unroll
  for (int ra = 0; ra < 4; ++ra)
#pragma unroll
    for (int fb = 0; fb < 4; ++fb)
#pragma unroll
      for (int j = 0; j < 4; ++j) {
        int row = ra * 16 + g * 4 + j;
        int c = w * 64 + fb * 16 + l15;
        ob[(size_t)(s0 + row) * 512 + c] = f2bf(accp[ra][fb][j] * li[ra][j]);
      }
}

// ---------------- K3: output projection GEMM ----------------
__global__ __launch_bounds__(256, 2) void k_gemm_out(
    const u16* __restrict__ o, const u16* __restrict__ woT,
    const float* __restrict__ bo, float* __restrict__ out) {
  __shared__ u16 la[128 * 64];
  __shared__ u16 lb[128 * 64];
  int nt = blockIdx.x & 3, mt = blockIdx.x >> 2;
  int tid = threadIdx.x, lane = tid & 63, w = tid >> 6;
  int wr = w >> 1, wc = w & 1;
  int m0 = mt * 128, n0 = nt * 128;
  int b = m0 >> 10, s0l = m0 & 1023;
  f32x4 acc[4][4];
#pragma unroll
  for (int i = 0; i < 4; ++i)
#pragma unroll
    for (int j = 0; j < 4; ++j) acc[i][j] = (f32x4){0.f, 0.f, 0.f, 0.f};

  for (int kt = 0; kt < CDIM / 64; ++kt) {
    int k0 = kt * 64;
    int h = k0 >> 9, f0 = k0 & 511;
#pragma unroll
    for (int i = 0; i < 4; ++i) {
      int chunk = i * 256 + w * 64 + lane;
      int row = chunk >> 3, c8 = (chunk & 7) << 3;
      u16* ldsta = la + (size_t)(i * 256 + w * 64) * 8;
      u16* ldstb = lb + (size_t)(i * 256 + w * 64) * 8;
      gl_lds16(o + (size_t)b * 4194304 + (size_t)h * 524288 +
                   (size_t)(s0l + row) * 512 + f0 + c8, ldsta);
      gl_lds16(woT + (size_t)(n0 + row) * 4096 + k0 + c8, ldstb);
    }
    __syncthreads();
#pragma unroll
    for (int kk = 0; kk < 2; ++kk) {
      bf16x8 af[4], bg[4];
#pragma unroll
      for (int mi = 0; mi < 4; ++mi)
        af[mi] = *(const bf16x8*)(la + (wr * 64 + mi * 16 + (lane & 15)) * 64 +
                                  kk * 32 + ((lane >> 4) << 3));
#pragma unroll
      for (int ni = 0; ni < 4; ++ni)
        bg[ni] = *(const bf16x8*)(lb + (wc * 64 + ni * 16 + (lane & 15)) * 64 +
                                  kk * 32 + ((lane >> 4) << 3));
#pragma unroll
      for (int mi = 0; mi < 4; ++mi)
#pragma unroll
        for (int ni = 0; ni < 4; ++ni)
          acc[mi][ni] = __builtin_amdgcn_mfma_f32_16x16x32_bf16(
              af[mi], bg[ni], acc[mi][ni], 0, 0, 0);
    }
    __syncthreads();
  }
#pragma unroll
  for (int mi = 0; mi < 4; ++mi)
#pragma unroll
    for (int ni = 0; ni < 4; ++ni)
#pragma unroll
      for (int j = 0; j < 4; ++j) {
        int r = wr * 64 + mi * 16 + ((lane >> 4) << 2) + j;
        int c = wc * 64 + ni * 16 + (lane & 15);
        out[(size_t)(m0 + r) * 512 + n0 + c] = acc[mi][ni][j] + bo[n0 + c];
      }
}

extern "C" void kernel_launch(void* const* d_in, const int* in_sizes, int n_in,
                              void* d_out, int out_size, void* d_ws, size_t ws_size,
                              hipStream_t stream) {
  const float* x  = (const float*)d_in[0];
  const float* Wq = (const float*)d_in[1];
  const float* Wk = (const float*)d_in[2];
  const float* Wv = (const float*)d_in[3];
  const float* bq = (const float*)d_in[4];
  const float* bk = (const float*)d_in[5];
  const float* bv = (const float*)d_in[6];
  const float* Wo = (const float*)d_in[7];
  const float* bo = (const float*)d_in[8];
  float* out = (float*)d_out;
  char* ws = (char*)d_ws;
  u16* xb  = (u16*)(ws);                  //  8 MB
  u16* wt  = (u16*)(ws + 8388608);        // 12 MB
  u16* woT = (u16*)(ws + 20971520);       //  4 MB
  u16* qo  = (u16*)(ws + 25165824);       // 64 MB  q, later o
  u16* kws = (u16*)(ws + 92274688);       // 64 MB  k
  u16* vT  = (u16*)(ws + 159383552);      // 64 MB  v^T [b][h][f][t]

  k_cvt_x<<<4096, 256, 0, stream>>>(x, xb);
  k_transpose<<<dim3(16, 16, 8), 256, 0, stream>>>(Wq, wt + 0,       512, 512);
  k_transpose<<<dim3(16, 16, 8), 256, 0, stream>>>(Wk, wt + 2097152, 512, 512);
  k_transpose<<<dim3(16, 16, 8), 256, 0, stream>>>(Wv, wt + 4194304, 512, 512);
  k_transpose<<<dim3(16, 128, 1), 256, 0, stream>>>(Wo, woT, 4096, 512);
  k_gemm_qkv<<<6144, 256, 0, stream>>>(xb, wt, bq, bk, bv, qo, kws, vT);
  k_attn<<<1024, 512, 0, stream>>>(qo, kws, vT, qo);
  k_gemm_out<<<256, 256, 0, stream>>>(qo, woT, bo, out);
}